// Round 3
// baseline (309.009 us; speedup 1.0000x reference)
//
#include <hip/hip_runtime.h>
#include <hip/hip_bf16.h>
#include <stdint.h>

// B=4, N=8192, E=1024, D=64 ; ROWS = 32768
// out = ((x@wq^T) @ (K^T V) * sqrt(3/64)) @ wo^T
// Precision: weights exact in bf16; activations split hi/lo bf16 -> fp32 MFMA acc.
//
// R3 structure: K1/K3 are HBM-streaming kernels (MFMA duty ~15%).
//  - B-matrices (384KB + 128KB bf16) live in L2, read directly as MFMA
//    fragments (64B-coalesced per 4-lane group) -> no W staging, no 2nd barrier.
//  - K1: 32rx192c tiles, 1024 blocks (4/CU), 1 barrier/step, loads issued
//    after the barrier and consumed before the next (drain-immune).
//  - Q passed K1->K3 as fp32; hi/lo split done once per block in K3.

typedef __bf16 bf16x8 __attribute__((ext_vector_type(8)));
typedef float  f32x4  __attribute__((ext_vector_type(4)));

#define MFMA_BF16(A, Bb, C) __builtin_amdgcn_mfma_f32_16x16x32_bf16(A, Bb, C, 0, 0, 0)

__device__ __forceinline__ int swz8(int row, int slot) { return (slot ^ (row & 7)) << 3; }

__device__ __forceinline__ void gload_lds16(const void* g, void* l) {
    __builtin_amdgcn_global_load_lds(
        (const __attribute__((address_space(1))) unsigned int*)g,
        (__attribute__((address_space(3))) unsigned int*)l, 16, 0, 0);
}

// ---------------------------------------------------------------------------
// P0: flat fp32->bf16 cast of [wq|wk|wv] -> Wb[192][1024] and wo -> Wob[1024][64].
// Wb/Wob are contiguous in ws, so dst indexing is flat.
// ---------------------------------------------------------------------------
__global__ __launch_bounds__(128) void prep_kernel(
    const float* __restrict__ wq, const float* __restrict__ wk,
    const float* __restrict__ wv, const float* __restrict__ wo,
    __bf16* __restrict__ Wb)
{
    const int gid = blockIdx.x * 128 + threadIdx.x;      // 0..32767
    const int e0  = gid * 8;                             // 0..262136
    const float* src = (e0 < 65536)  ? wq + e0
                     : (e0 < 131072) ? wk + (e0 - 65536)
                     : (e0 < 196608) ? wv + (e0 - 131072)
                                     : wo + (e0 - 196608);
    float w[8];
    *(float4*)&w[0] = *(const float4*)(src);
    *(float4*)&w[4] = *(const float4*)(src + 4);
    bf16x8 wb;
#pragma unroll
    for (int j = 0; j < 8; ++j) wb[j] = (__bf16)w[j];
    *(bf16x8*)&Wb[e0] = wb;
}

// ---------------------------------------------------------------------------
// K1: QKV GEMM.  C[32768 x 192] = split(x) @ Wb^T.
// 1024 blocks (4/CU) x 256 thr (4 waves, 1m x 4n), tile 32r x 192c, BK=64.
// x: regs -> hi/lo split -> swizzled LDS (double-buffered, 16 KB total).
// B-fragments read directly from L2-resident Wb.
// ---------------------------------------------------------------------------
__global__ __launch_bounds__(256) void qkv_kernel(
    const float* __restrict__ x, const __bf16* __restrict__ Wb,
    float* __restrict__ Qf, float* __restrict__ Kf, float* __restrict__ Vf)
{
    __shared__ __bf16 xh[2][32 * 64];
    __shared__ __bf16 xl[2][32 * 64];

    const int tid  = threadIdx.x;
    const int lane = tid & 63;
    const int wid  = tid >> 6;          // 0..3 = col group of 48
    const int lr   = lane & 15;
    const int kg   = lane >> 4;
    const int row0 = blockIdx.x * 32;

    const int sr = tid >> 3;            // staging row 0..31
    const int f8 = tid & 7;             // staging k-slot

    f32x4 acc[2][3];
#pragma unroll
    for (int i = 0; i < 2; ++i)
#pragma unroll
        for (int j = 0; j < 3; ++j) acc[i][j] = (f32x4){0.f, 0.f, 0.f, 0.f};

    float xv[8], xn[8];

#define LOAD_X(dst, stp)                                                        \
    {                                                                           \
        const float* src_ = &x[(size_t)(row0 + sr) * 1024 + (stp) * 64 + f8 * 8]; \
        *(float4*)&dst[0] = *(const float4*)(src_);                             \
        *(float4*)&dst[4] = *(const float4*)(src_ + 4);                         \
    }

    LOAD_X(xv, 0);

#pragma unroll 2
    for (int step = 0; step < 16; ++step) {
        const int cur = step & 1;
        // convert current x regs -> hi/lo, write swizzled LDS
        {
            bf16x8 h, l;
#pragma unroll
            for (int j = 0; j < 8; ++j) {
                const float v = xv[j];
                const unsigned int bb = __float_as_uint(v);
                h[j] = __builtin_bit_cast(__bf16, (unsigned short)(bb >> 16));
                l[j] = (__bf16)(v - __uint_as_float(bb & 0xffff0000u));
            }
            const int off = sr * 64 + swz8(sr, f8);
            *(bf16x8*)&xh[cur][off] = h;
            *(bf16x8*)&xl[cur][off] = l;
        }
        __syncthreads();
        if (step < 15) LOAD_X(xn, step + 1);     // in flight across MFMA phase

#pragma unroll
        for (int ks = 0; ks < 2; ++ks) {
            const int slot = ks * 4 + kg;
            bf16x8 Ah[2], Al[2], Bw[3];
#pragma unroll
            for (int am = 0; am < 2; ++am) {
                const int row = am * 16 + lr;
                Ah[am] = *(const bf16x8*)&xh[cur][row * 64 + swz8(row, slot)];
                Al[am] = *(const bf16x8*)&xl[cur][row * 64 + swz8(row, slot)];
            }
#pragma unroll
            for (int bn = 0; bn < 3; ++bn) {
                const int col = wid * 48 + bn * 16 + lr;
                Bw[bn] = *(const bf16x8*)&Wb[(size_t)col * 1024 + step * 64 + slot * 8];
            }
#pragma unroll
            for (int am = 0; am < 2; ++am)
#pragma unroll
                for (int bn = 0; bn < 3; ++bn) {
                    acc[am][bn] = MFMA_BF16(Ah[am], Bw[bn], acc[am][bn]);
                    acc[am][bn] = MFMA_BF16(Al[am], Bw[bn], acc[am][bn]);
                }
        }
#pragma unroll
        for (int j = 0; j < 8; ++j) xv[j] = xn[j];
    }
#undef LOAD_X

    // epilogue: C/D layout col=lane&15, row=(lane>>4)*4+reg ; fp32 stores
#pragma unroll
    for (int am = 0; am < 2; ++am)
#pragma unroll
        for (int bn = 0; bn < 3; ++bn) {
            const int col  = wid * 48 + bn * 16 + lr;
            const int rowb = row0 + am * 16 + kg * 4;
            float* dst = (col < 64) ? Qf : (col < 128) ? Kf : Vf;
            const int cc = col & 63;
#pragma unroll
            for (int r = 0; r < 4; ++r)
                dst[(size_t)(rowb + r) * 64 + cc] = acc[am][bn][r];
        }
}

// ---------------------------------------------------------------------------
// K2: partial energy over 128-row blocks.  part[blk][d][e] = sum K[n,d]V[n,e]
// ---------------------------------------------------------------------------
__global__ __launch_bounds__(512) void energy_partial_kernel(
    const float* __restrict__ Kf, const float* __restrict__ Vf,
    float* __restrict__ part)
{
    __shared__ float lK[32 * 64];
    __shared__ float lV[32 * 64];
    const int tid  = threadIdx.x;
    const int lane = tid & 63;
    const int wid  = tid >> 6;
    const int d    = tid >> 3;           // 0..63
    const int e0   = (tid & 7) * 8;      // 0..56
    const int row0 = blockIdx.x * 128;

    float acc[8] = {0.f, 0.f, 0.f, 0.f, 0.f, 0.f, 0.f, 0.f};

    for (int c = 0; c < 4; ++c) {
        const size_t boff = (size_t)(row0 + c * 32) * 256 + wid * 1024 + (lane << 4);
        gload_lds16((const char*)Kf + boff, (char*)lK + wid * 1024);
        gload_lds16((const char*)Vf + boff, (char*)lV + wid * 1024);
        __syncthreads();
        for (int n = 0; n < 32; ++n) {
            const float kv = lK[n * 64 + d];
            const float4 a = *(const float4*)&lV[n * 64 + e0];
            const float4 b = *(const float4*)&lV[n * 64 + e0 + 4];
            acc[0] += kv * a.x; acc[1] += kv * a.y; acc[2] += kv * a.z; acc[3] += kv * a.w;
            acc[4] += kv * b.x; acc[5] += kv * b.y; acc[6] += kv * b.z; acc[7] += kv * b.w;
        }
        __syncthreads();
    }
    float* p = part + (size_t)blockIdx.x * 4096 + d * 64 + e0;
    *(float4*)&p[0] = make_float4(acc[0], acc[1], acc[2], acc[3]);
    *(float4*)&p[4] = make_float4(acc[4], acc[5], acc[6], acc[7]);
}

// K2b: reduce partials, fold sqrt(3/64), emit E^T as swizzled bf16 hi/lo.
__global__ __launch_bounds__(256) void energy_reduce_kernel(
    const float* __restrict__ part, __bf16* __restrict__ Eth, __bf16* __restrict__ Etl)
{
    const int b    = blockIdx.x >> 4;
    const int elem = ((blockIdx.x & 15) << 8) + threadIdx.x;   // d*64+e
    float s = 0.f;
#pragma unroll 8
    for (int c = 0; c < 64; ++c)
        s += part[(size_t)(b * 64 + c) * 4096 + elem];
    s *= 0.2165063509461097f;                                  // sqrt(3/64)
    const int d = elem >> 6, e = elem & 63;
    const __bf16 h = (__bf16)s;
    const __bf16 l = (__bf16)(s - (float)h);
    const size_t o = (size_t)b * 4096 + e * 64 + swz8(e, d >> 3) + (d & 7);
    Eth[o] = h; Etl[o] = l;
}

// ---------------------------------------------------------------------------
// K3: out = ctx @ wo^T, ctx = Q @ E.  64-row tiles, 512 blocks, 8 waves.
// Q fp32 staged+split once per block; E^T and Wob read from L2 as fragments.
// ---------------------------------------------------------------------------
__global__ __launch_bounds__(512) void out_kernel(
    const float* __restrict__ Qf,
    const __bf16* __restrict__ Eth, const __bf16* __restrict__ Etl,
    const __bf16* __restrict__ Wob, float* __restrict__ out)
{
    __shared__ __bf16 qh[64 * 64];
    __shared__ __bf16 ql[64 * 64];
    __shared__ __bf16 ch[64 * 64];
    __shared__ __bf16 cl[64 * 64];

    const int tid  = threadIdx.x;
    const int lane = tid & 63;
    const int wid  = tid >> 6;
    const int lr   = lane & 15;
    const int kg   = lane >> 4;
    const int wm   = wid >> 2;          // 0..1
    const int wn   = wid & 3;           // 0..3
    const int row0 = blockIdx.x * 64;
    const int b    = blockIdx.x >> 7;   // 128 blocks per batch

    // ---- stage Q: fp32 -> hi/lo bf16, swizzled (once per block) ----
    {
        const int r  = tid >> 3;         // 0..63
        const int f8 = tid & 7;
        const float* src = &Qf[(size_t)(row0 + r) * 64 + f8 * 8];
        float v[8];
        *(float4*)&v[0] = *(const float4*)(src);
        *(float4*)&v[4] = *(const float4*)(src + 4);
        bf16x8 h, l;
#pragma unroll
        for (int j = 0; j < 8; ++j) {
            const unsigned int bb = __float_as_uint(v[j]);
            h[j] = __builtin_bit_cast(__bf16, (unsigned short)(bb >> 16));
            l[j] = (__bf16)(v[j] - __uint_as_float(bb & 0xffff0000u));
        }
        const int off = r * 64 + swz8(r, f8);
        *(bf16x8*)&qh[off] = h;
        *(bf16x8*)&ql[off] = l;
    }
    __syncthreads();

    // ---- ctx = Q @ E via MFMA; each wave: 32 rows x 16 e-cols ----
    f32x4 cacc[2];
    cacc[0] = (f32x4){0.f, 0.f, 0.f, 0.f};
    cacc[1] = (f32x4){0.f, 0.f, 0.f, 0.f};
#pragma unroll
    for (int ks = 0; ks < 2; ++ks) {
        const int slot = ks * 4 + kg;
        const int e    = wn * 16 + lr;
        const bf16x8 Bh = *(const bf16x8*)&Eth[(size_t)b * 4096 + e * 64 + swz8(e, slot)];
        const bf16x8 Bl = *(const bf16x8*)&Etl[(size_t)b * 4096 + e * 64 + swz8(e, slot)];
#pragma unroll
        for (int am = 0; am < 2; ++am) {
            const int row = wm * 32 + am * 16 + lr;
            const bf16x8 Ah = *(const bf16x8*)&qh[row * 64 + swz8(row, slot)];
            const bf16x8 Al = *(const bf16x8*)&ql[row * 64 + swz8(row, slot)];
            cacc[am] = MFMA_BF16(Ah, Bh, cacc[am]);
            cacc[am] = MFMA_BF16(Ah, Bl, cacc[am]);
            cacc[am] = MFMA_BF16(Al, Bh, cacc[am]);
        }
    }
    // write ctx (C-layout transpose) hi/lo into swizzled LDS
#pragma unroll
    for (int am = 0; am < 2; ++am)
#pragma unroll
        for (int r = 0; r < 4; ++r) {
            const int n  = wm * 32 + am * 16 + kg * 4 + r;
            const int dd = wn * 16 + lr;
            const float v  = cacc[am][r];
            const __bf16 h = (__bf16)v;
            const __bf16 l = (__bf16)(v - (float)h);
            const int off = n * 64 + swz8(n, dd >> 3) + (dd & 7);
            ch[off] = h; cl[off] = l;
        }
    __syncthreads();

    // ---- out GEMM: each wave 32 rows x 256 cols; A held in regs ----
    bf16x8 Ah[2][2], Al[2][2];
#pragma unroll
    for (int am = 0; am < 2; ++am)
#pragma unroll
        for (int ks = 0; ks < 2; ++ks) {
            const int row  = wm * 32 + am * 16 + lr;
            const int slot = ks * 4 + kg;
            Ah[am][ks] = *(const bf16x8*)&ch[row * 64 + swz8(row, slot)];
            Al[am][ks] = *(const bf16x8*)&cl[row * 64 + swz8(row, slot)];
        }
#pragma unroll
    for (int g = 0; g < 4; ++g) {
        f32x4 oacc[2][4];
#pragma unroll
        for (int i = 0; i < 2; ++i)
#pragma unroll
            for (int j = 0; j < 4; ++j) oacc[i][j] = (f32x4){0.f, 0.f, 0.f, 0.f};
#pragma unroll
        for (int ks = 0; ks < 2; ++ks) {
            bf16x8 Bw[4];
#pragma unroll
            for (int bn = 0; bn < 4; ++bn) {
                const int col = wn * 256 + g * 64 + bn * 16 + lr;
                Bw[bn] = *(const bf16x8*)&Wob[(size_t)col * 64 + ks * 32 + kg * 8];
            }
#pragma unroll
            for (int am = 0; am < 2; ++am)
#pragma unroll
                for (int bn = 0; bn < 4; ++bn) {
                    oacc[am][bn] = MFMA_BF16(Ah[am][ks], Bw[bn], oacc[am][bn]);
                    oacc[am][bn] = MFMA_BF16(Al[am][ks], Bw[bn], oacc[am][bn]);
                }
        }
#pragma unroll
        for (int am = 0; am < 2; ++am)
#pragma unroll
            for (int bn = 0; bn < 4; ++bn) {
                const int gcol = wn * 256 + g * 64 + bn * 16 + lr;
                const int grow = row0 + wm * 32 + am * 16 + kg * 4;
#pragma unroll
                for (int r = 0; r < 4; ++r)
                    __builtin_nontemporal_store(oacc[am][bn][r],
                        &out[(size_t)(grow + r) * 1024 + gcol]);
            }
    }
}

extern "C" void kernel_launch(void* const* d_in, const int* in_sizes, int n_in,
                              void* d_out, int out_size, void* d_ws, size_t ws_size,
                              hipStream_t stream)
{
    const float* x  = (const float*)d_in[0];
    const float* wq = (const float*)d_in[1];
    const float* wk = (const float*)d_in[2];
    const float* wv = (const float*)d_in[3];
    const float* wo = (const float*)d_in[4];
    float* out = (float*)d_out;

    char* ws = (char*)d_ws;
    float*  Qf   = (float*)(ws);                          // 8 MB
    float*  Kf   = (float*)(ws + 8388608);                // 8 MB
    float*  Vf   = (float*)(ws + 16777216);               // 8 MB
    float*  part = (float*)(ws + 25165824);               // 4 MB
    __bf16* Wb   = (__bf16*)(ws + 29360128);              // 384 KB [192][1024]
    __bf16* Wob  = (__bf16*)(ws + 29753344);              // 128 KB [1024][64] (contiguous after Wb)
    __bf16* Eth  = (__bf16*)(ws + 30408704);              // 32 KB
    __bf16* Etl  = (__bf16*)(ws + 30441472);              // 32 KB

    prep_kernel<<<256, 128, 0, stream>>>(wq, wk, wv, wo, Wb);
    qkv_kernel<<<1024, 256, 0, stream>>>(x, Wb, Qf, Kf, Vf);
    energy_partial_kernel<<<256, 512, 0, stream>>>(Kf, Vf, part);
    energy_reduce_kernel<<<64, 256, 0, stream>>>(part, Eth, Etl);
    out_kernel<<<512, 512, 0, stream>>>(Qf, Eth, Etl, Wob, out);
}